// Round 2
// baseline (241.701 us; speedup 1.0000x reference)
//
#include <hip/hip_runtime.h>

// FFTConvNet: out[b,o] = IFFT2( M · sum_i X^[(b+8)%16, i] · W^[(o+32)%64, i] ) + bias[o]
// fftshift(no axes) shifts ALL dims -> batch roll 8, Cout roll 32; Cin rolls cancel.
// Disk mask fy^2+fx^2<=900. Half-spectrum: fy(t) in [0,30] (31), fx in [-30,30] (61), f2 = fxp*31+t.
// k3 is an MFMA kernel: per freq, Out[16b x 64o] complex = A[16x128] * B[128x128] real-packed.
// k12 Cls geometry: row stride 70 (write banks 2-way=free), plane stride 2244 (2244%32=4 ->
//   the 4 r-class reads hit disjoint bank quads). Reads are 4x b64 (70*xx breaks 16B align).
// WtB layout (16KB/freq, fragment-order): u32 idx = f2*4096 + (o>>3)*512 + (i>>4)*128
//                                                  + (((i>>2)&3)*8 + (o&7))*4 + (i&3)
// F layout [f2][16 b][128 col] f32 (col=2o re, 2o+1 im); k45 gathers strided (L2/L3-served).
// ws: WtB u32 [0, 7745536) ; X2 float [7745536, +3872768) ; F float [11618304, +3872768).

#define PI2_128 0.04908738521234052f  // 2*pi/128
#define NF 1891

typedef __attribute__((ext_vector_type(8))) short bf16x8;
typedef __attribute__((ext_vector_type(4))) float f32x4;

// fxp list ordered by class r=(fxp+2)&3 (= fx mod 4): c0(15), c1(15), c2(16), c3(15), 3 dummies.
__device__ const int k_flist[64] = {
    2, 6, 10, 14, 18, 22, 26, 30, 34, 38, 42, 46, 50, 54, 58,
    3, 7, 11, 15, 19, 23, 27, 31, 35, 39, 43, 47, 51, 55, 59,
    0, 4, 8, 12, 16, 20, 24, 28, 32, 36, 40, 44, 48, 52, 56, 60,
    1, 5, 9, 13, 17, 21, 25, 29, 33, 37, 41, 45, 49, 53, 57,
    0, 0, 0};

__device__ inline unsigned bf16_rne(float v) {
  unsigned u = __float_as_uint(v);
  return (u + 0x7FFFu + ((u >> 16) & 1u)) >> 16;
}

__device__ inline bf16x8 mk_bf16x8(unsigned a, unsigned b, unsigned c, unsigned d) {
  union { unsigned u[4]; bf16x8 v; } x;
  x.u[0] = a; x.u[1] = b; x.u[2] = c; x.u[3] = d;
  return x.v;
}

// ---------------- K0: W^ precompute (bf16), separable 3x3 twiddles ----------------
// Stores into MFMA-fragment order (see header comment).
__global__ __launch_bounds__(256) void k0_what(const float* __restrict__ w,
                                               unsigned* __restrict__ Wt) {
  const int tid = threadIdx.x;
  const int fxp = blockIdx.x >> 4;  // 0..60
  const int ig = blockIdx.x & 15;
  const int il = tid >> 6;
  const int o = tid & 63;
  const int i = ig * 4 + il;
  const int op = (o + 32) & 63;
  const float* wp = w + (size_t)(op * 64 + i) * 9;
  float w9[9];
#pragma unroll
  for (int k = 0; k < 9; ++k) w9[k] = wp[k];

  const float fx = (float)(fxp - 30);
  float sn, cs;
  __sincosf(fx * PI2_128, &sn, &cs);
  const float e1x = cs, e1y = -sn;
  const float e2x = e1x * e1x - e1y * e1y, e2y = 2.f * e1x * e1y;
  float rxr[3], rxi[3];
#pragma unroll
  for (int ky = 0; ky < 3; ++ky) {
    rxr[ky] = w9[ky * 3] + w9[ky * 3 + 1] * e1x + w9[ky * 3 + 2] * e2x;
    rxi[ky] = w9[ky * 3 + 1] * e1y + w9[ky * 3 + 2] * e2y;
  }
  float pyx = 1.f, pyy = 0.f;
  const float stx = 0.9987954562f, sty = -0.04906767433f;
  // fragment-order base: (o>>3)*512 + (i>>4)*128 + (((i>>2)&3)*8 + (o&7))*4 + (i&3)
  unsigned* Wb = Wt + (size_t)(fxp * 31) * 4096 + (o >> 3) * 512 + (i >> 4) * 128 +
                 (((i >> 2) & 3) * 8 + (o & 7)) * 4 + (i & 3);
  for (int fy = 0; fy < 31; ++fy) {
    float p2x = pyx * pyx - pyy * pyy, p2y = 2.f * pyx * pyy;
    float Wre = rxr[0] + (rxr[1] * pyx - rxi[1] * pyy) + (rxr[2] * p2x - rxi[2] * p2y);
    float Wim = rxi[0] + (rxr[1] * pyy + rxi[1] * pyx) + (rxr[2] * p2y + rxi[2] * p2x);
    Wb[(size_t)fy * 4096] = bf16_rne(Wre) | (bf16_rne(Wim) << 16);
    float nx = pyx * stx - pyy * sty;
    pyy = pyx * sty + pyy * stx;
    pyx = nx;
  }
}

// ---------------- K12: fused forward DFT (radix-4 folded both axes) ----------------
__global__ __launch_bounds__(256) void k12_fwd(const float* __restrict__ x,
                                               float* __restrict__ X2) {
  // Cls[r*2244 + x*70 + 2t(+1)]: 4 folded class-planes for phase B.
  // row stride 70 -> write banks (16g+6h): 2-way = free; plane stride 2244 (%32==4)
  // -> the 4 r-class reads per half-wave land on disjoint bank quads.
  __shared__ __align__(16) float Cls[8968];
  const int bi = blockIdx.x;
  const int tid = threadIdx.x;
  const float* img = x + (size_t)bi * 16384;

  // Phase A: y-DFT, radix-4 fold over y. Thread owns x in {xg,+32,+64,+96}, 4 freqs.
  {
    const int tg = tid >> 5;  // 0..7
    const int xg = tid & 31;
    const int t_[4] = {4 * tg, 4 * tg + 2, 2 * tg + 1, 2 * tg + 17};  // t=31 computed, discarded
    const float sgn = (tg & 1) ? 1.f : -1.f;  // (-i)^t for odd t: -i (t%4==1) / +i (t%4==3)
    float pc[4], ps[4], stc[4], sts[4];
#pragma unroll
    for (int f = 0; f < 4; ++f) {
      __sincosf((float)t_[f] * PI2_128, &sts[f], &stc[f]);
      pc[f] = 1.f;
      ps[f] = 0.f;
    }
    float ar_[4][4] = {{0.f}}, ai_[4][4] = {{0.f}};  // [freq][m]
    for (int y = 0; y < 32; ++y) {
      float v[4][4];
#pragma unroll
      for (int k = 0; k < 4; ++k)
#pragma unroll
        for (int m = 0; m < 4; ++m) v[k][m] = img[(y + 32 * k) * 128 + xg + 32 * m];
#pragma unroll
      for (int m = 0; m < 4; ++m) {
        float s = v[0][m] + v[2][m], d = v[0][m] - v[2][m];
        float s2 = v[1][m] + v[3][m], d2 = (v[1][m] - v[3][m]) * sgn;
        float a0 = s + s2, a1 = s - s2;
        ar_[0][m] += a0 * pc[0];
        ai_[0][m] -= a0 * ps[0];
        ar_[1][m] += a1 * pc[1];
        ai_[1][m] -= a1 * ps[1];
        ar_[2][m] += d * pc[2] + d2 * ps[2];
        ai_[2][m] += -d * ps[2] + d2 * pc[2];
        ar_[3][m] += d * pc[3] + d2 * ps[3];
        ai_[3][m] += -d * ps[3] + d2 * pc[3];
      }
#pragma unroll
      for (int f = 0; f < 4; ++f) {
        float c = pc[f], s = ps[f];
        pc[f] = c * stc[f] - s * sts[f];
        ps[f] = s * stc[f] + c * sts[f];
      }
    }
    // In-register x-butterfly (classes for phase B's fx fold), write 4 planes.
#pragma unroll
    for (int f = 0; f < 4; ++f) {
      int t = t_[f];
      float Ar = ar_[f][0] + ar_[f][2], Ai = ai_[f][0] + ai_[f][2];
      float Br = ar_[f][0] - ar_[f][2], Bi = ai_[f][0] - ai_[f][2];
      float Cr = ar_[f][1] + ar_[f][3], Ci = ai_[f][1] + ai_[f][3];
      float Dr = ar_[f][1] - ar_[f][3], Di = ai_[f][1] - ai_[f][3];
      float* base = Cls + xg * 70 + 2 * t;
      *(float2*)(base + 0 * 2244) = make_float2(Ar + Cr, Ai + Ci);  // r=0: A+C
      *(float2*)(base + 1 * 2244) = make_float2(Br + Di, Bi - Dr);  // r=1: B-iD
      *(float2*)(base + 2 * 2244) = make_float2(Ar - Cr, Ai - Ci);  // r=2: A-C
      *(float2*)(base + 3 * 2244) = make_float2(Br - Di, Bi + Dr);  // r=3: B+iD
    }
  }
  __syncthreads();

  // Phase B: x-DFT on folded planes (32 samples per freq) + disk mask.
  {
    const int tg2 = tid >> 5;  // t-quad: t = 4*tg2 + tt
    const int fxg = tid & 31;
    float accr[2][4] = {{0.f}}, acci[2][4] = {{0.f}};
    int fxp_[2], r_[2];
    float pc2[2], ps2[2], stc2[2], sts2[2];
#pragma unroll
    for (int u = 0; u < 2; ++u) {
      fxp_[u] = k_flist[2 * fxg + u];
      r_[u] = (fxp_[u] + 2) & 3;
      float fx = (float)(fxp_[u] - 30);
      __sincosf(fx * PI2_128, &sts2[u], &stc2[u]);
      pc2[u] = 1.f;
      ps2[u] = 0.f;
    }
    for (int xx = 0; xx < 32; ++xx) {
#pragma unroll
      for (int u = 0; u < 2; ++u) {
        const float* bp = Cls + r_[u] * 2244 + xx * 70 + 8 * tg2;
        float2 p0 = *(const float2*)(bp);
        float2 p1 = *(const float2*)(bp + 2);
        float2 p2 = *(const float2*)(bp + 4);
        float2 p3 = *(const float2*)(bp + 6);
        float zr[4] = {p0.x, p1.x, p2.x, p3.x};
        float zi[4] = {p0.y, p1.y, p2.y, p3.y};
        float c = pc2[u], s = ps2[u];
#pragma unroll
        for (int tt = 0; tt < 4; ++tt) {
          accr[u][tt] += zr[tt] * c + zi[tt] * s;
          acci[u][tt] += zi[tt] * c - zr[tt] * s;
        }
        pc2[u] = c * stc2[u] - s * sts2[u];
        ps2[u] = s * stc2[u] + c * sts2[u];
      }
    }
    float2* X2c = (float2*)X2 + (size_t)bi * NF;
#pragma unroll
    for (int u = 0; u < 2; ++u) {
      if (2 * fxg + u >= 61) continue;
      int fxp = fxp_[u], fx = fxp - 30;
#pragma unroll
      for (int tt = 0; tt < 4; ++tt) {
        int t = 4 * tg2 + tt;
        if (t >= 31) continue;
        bool keep = (t * t + fx * fx) <= 900;
        X2c[fxp * 31 + t] =
            keep ? make_float2(accr[u][tt], acci[u][tt]) : make_float2(0.f, 0.f);
      }
    }
  }
}

// ---------------- K3: per-frequency channel mix via MFMA (bf16, X split hi/lo) ----
// One wave = one (freq, N-half). 2 waves/freq, 4 waves/block -> 2 freqs/block.
// Zero LDS, zero barriers. Writes F[f2][b][col] (col = 2o + re/im).
__global__ __launch_bounds__(256) void k3_mfma(const float* __restrict__ X2,
                                               const unsigned* __restrict__ WtB,
                                               float* __restrict__ F) {
  // bijective XCD-chunked blockIdx swizzle (m204 form) for L2 locality of X gathers
  const int nwg = (int)gridDim.x;
  const int orig = (int)blockIdx.x;
  const int xcd = orig & 7;
  const int q = nwg >> 3, r = nwg & 7;
  const int blk = (xcd < r ? xcd * (q + 1) : r * (q + 1) + (xcd - r) * q) + (orig >> 3);

  const int tid = (int)threadIdx.x;
  const int wv = tid >> 6;
  const int g = blk * 4 + wv;
  const int f2 = g >> 1;
  if (f2 >= NF) return;
  const int half = g & 1;
  const int lane = tid & 63;
  const int m = lane & 15;   // A-row (output batch) == B-col-within-tile
  const int lg = lane >> 4;  // k lane-group
  const int bs = (m + 8) & 15;
  const int co = m & 1;      // re/im column parity

  // ---- A: gather X[bs][i] (i = ks*16 + lg*4 + t) for this freq; split hi/lo bf16 ----
  float2 xv[4][4];
  const float2* Xc = (const float2*)X2;
#pragma unroll
  for (int ks = 0; ks < 4; ++ks)
#pragma unroll
    for (int t = 0; t < 4; ++t)
      xv[ks][t] = Xc[(size_t)(bs * 64 + ks * 16 + lg * 4 + t) * NF + f2];

  unsigned ahi[4][4], alo[4][4];
#pragma unroll
  for (int ks = 0; ks < 4; ++ks) {
#pragma unroll
    for (int t = 0; t < 4; ++t) {
      float xr = xv[ks][t].x, xi = xv[ks][t].y;
      unsigned hr = bf16_rne(xr), hi2 = bf16_rne(xi);
      float lr = xr - __uint_as_float(hr << 16);
      float li = xi - __uint_as_float(hi2 << 16);
      ahi[ks][t] = hr | (hi2 << 16);
      alo[ks][t] = bf16_rne(lr) | (bf16_rne(li) << 16);
    }
  }

  // ---- GEMM: acc[nt] over 4 N-tiles (this wave's N-half), K = 4 steps of 32 ----
  f32x4 acc[4];
#pragma unroll
  for (int nt = 0; nt < 4; ++nt) acc[nt] = {0.f, 0.f, 0.f, 0.f};

  const unsigned* Wb =
      WtB + (size_t)f2 * 4096 + half * 2048 + (lg * 8 + (m >> 1)) * 4;
#pragma unroll
  for (int ks = 0; ks < 4; ++ks) {
    bf16x8 bfr[4];
#pragma unroll
    for (int nt = 0; nt < 4; ++nt) {
      uint4 wq = *(const uint4*)(Wb + nt * 512 + ks * 128);
      unsigned b0, b1, b2, b3;
      if (co) {  // odd col: (Wi, Wr) = rot16(w)
        b0 = (wq.x >> 16) | (wq.x << 16);
        b1 = (wq.y >> 16) | (wq.y << 16);
        b2 = (wq.z >> 16) | (wq.z << 16);
        b3 = (wq.w >> 16) | (wq.w << 16);
      } else {   // even col: (Wr, -Wi) = w ^ signbit(hi)
        b0 = wq.x ^ 0x80000000u;
        b1 = wq.y ^ 0x80000000u;
        b2 = wq.z ^ 0x80000000u;
        b3 = wq.w ^ 0x80000000u;
      }
      bfr[nt] = mk_bf16x8(b0, b1, b2, b3);
    }
    bf16x8 ah = mk_bf16x8(ahi[ks][0], ahi[ks][1], ahi[ks][2], ahi[ks][3]);
    bf16x8 al = mk_bf16x8(alo[ks][0], alo[ks][1], alo[ks][2], alo[ks][3]);
#pragma unroll
    for (int nt = 0; nt < 4; ++nt)
      acc[nt] = __builtin_amdgcn_mfma_f32_16x16x32_bf16(ah, bfr[nt], acc[nt], 0, 0, 0);
#pragma unroll
    for (int nt = 0; nt < 4; ++nt)
      acc[nt] = __builtin_amdgcn_mfma_f32_16x16x32_bf16(al, bfr[nt], acc[nt], 0, 0, 0);
  }

  // ---- store: D row = lg*4 + rr (batch), col = half*64 + nt*16 + m ----
  float* Fo = F + (size_t)f2 * 2048 + half * 64 + m;
#pragma unroll
  for (int nt = 0; nt < 4; ++nt)
#pragma unroll
    for (int rr = 0; rr < 4; ++rr)
      Fo[(lg * 4 + rr) * 128 + nt * 16] = acc[nt][rr];
}

// ---------------- K45: inverse (radix-4 fold in x, parity fold in y) + bias ----------------
__global__ __launch_bounds__(256) void k45_out(const float* __restrict__ F,
                                               const float* __restrict__ bias,
                                               float* __restrict__ out) {
  __shared__ __align__(16) float2 tw[128];  // e^{+2pi i m/128}
  __shared__ __align__(16) float U[61 * 132];
  __shared__ __align__(16) float TF[3904];  // union: Fl (phase<=1), then T
  const int b = blockIdx.x >> 6;
  const int o = blockIdx.x & 63;
  const int tid = threadIdx.x;
  float2* Fl = (float2*)TF;
  // F layout is [f2][16 b][64 o] float2 -> gather with stride 1024 float2s.
  const float2* Fc = (const float2*)F + (size_t)(b * 64 + o);
  if (tid < 128) {
    float sv, cv;
    __sincosf((float)tid * PI2_128, &sv, &cv);
    tw[tid] = make_float2(cv, sv);
  }
  for (int j = tid; j < NF; j += 256) Fl[j] = Fc[(size_t)j * 1024];
  __syncthreads();

  // Phase 1: inverse-x with output fold H(x+32k) = sum_r i^{rk} S_r
  {
    const int fy = tid & 31;
    const int xg = tid >> 3 >> 2;  // tid>>5: 0..7
    if (fy < 31) {
      float Sr[4][4] = {{0.f}}, Si[4][4] = {{0.f}};  // [r][j]
      float pr[4], pi[4], cr[4], ci[4];
#pragma unroll
      for (int j = 0; j < 4; ++j) {
        int xj = 4 * xg + j;
        float2 st = tw[xj];
        cr[j] = st.x;
        ci[j] = st.y;
        float2 p0 = tw[(-30 * xj) & 127];
        pr[j] = p0.x;
        pi[j] = p0.y;
      }
      const float2* Frow = Fl + fy;
      for (int f4 = 0; f4 < 60; f4 += 4) {
#pragma unroll
        for (int ss = 0; ss < 4; ++ss) {
          const int r = (ss + 2) & 3;  // fxp class pattern 2,3,0,1
          float2 fv = Frow[(f4 + ss) * 31];
#pragma unroll
          for (int j = 0; j < 4; ++j) {
            Sr[r][j] += fv.x * pr[j] - fv.y * pi[j];
            Si[r][j] += fv.x * pi[j] + fv.y * pr[j];
            float np = pr[j] * cr[j] - pi[j] * ci[j];
            pi[j] = pi[j] * cr[j] + pr[j] * ci[j];
            pr[j] = np;
          }
        }
      }
      {  // fxp = 60, class 2
        float2 fv = Frow[60 * 31];
#pragma unroll
        for (int j = 0; j < 4; ++j) {
          Sr[2][j] += fv.x * pr[j] - fv.y * pi[j];
          Si[2][j] += fv.x * pi[j] + fv.y * pr[j];
        }
      }
#pragma unroll
      for (int j = 0; j < 4; ++j) {
        int xj = 4 * xg + j;
        float Er = Sr[0][j] + Sr[2][j], Ei = Si[0][j] + Si[2][j];
        float Fr = Sr[0][j] - Sr[2][j], Fi = Si[0][j] - Si[2][j];
        float Gr = Sr[1][j] + Sr[3][j], Gi = Si[1][j] + Si[3][j];
        float Hr = Sr[1][j] - Sr[3][j], Hi = Si[1][j] - Si[3][j];
        U[fy * 132 + xj] = Er + Gr;
        U[fy * 132 + xj + 32] = Fr - Hi;   // F4 + iH
        U[fy * 132 + xj + 64] = Er - Gr;
        U[fy * 132 + xj + 96] = Fr + Hi;   // F4 - iH
        if (fy >= 1) {
          U[(30 + fy) * 132 + xj] = Ei + Gi;
          U[(30 + fy) * 132 + xj + 32] = Fi + Hr;
          U[(30 + fy) * 132 + xj + 64] = Ei - Gi;
          U[(30 + fy) * 132 + xj + 96] = Fi - Hr;
        }
      }
    }
  }
  __syncthreads();
  // Build T[c][y] (y<64) over Fl's dead storage.
  {
    const float sc1 = 1.f / 16384.f;
    float* T = TF;
    for (int j = tid; j < 61 * 64; j += 256) {
      int c = j >> 6, y = j & 63;
      float val;
      if (c == 0) val = sc1;
      else if (c <= 30) val = 2.f * sc1 * tw[(c * y) & 127].x;
      else val = -2.f * sc1 * tw[((c - 30) * y) & 127].y;
      T[j] = val;
    }
  }
  __syncthreads();
  // Phase 2: inverse-y with parity fold (even c -> P, odd c -> Q); out[y]=P+Q, out[y+64]=P-Q
  {
    const float* T = TF;
    const int yg = tid >> 5;
    const int xg = tid & 31;
    const int y0 = yg * 8, x0 = xg * 4;
    float Pa[8][4] = {{0.f}}, Qa[8][4] = {{0.f}};
    for (int c = 0; c < 60; c += 2) {
      float tf0[8], tf1[8], uf0[4], uf1[4];
      *(float4*)&tf0[0] = *(const float4*)(&T[c * 64 + y0]);
      *(float4*)&tf0[4] = *(const float4*)(&T[c * 64 + y0 + 4]);
      *(float4*)&tf1[0] = *(const float4*)(&T[(c + 1) * 64 + y0]);
      *(float4*)&tf1[4] = *(const float4*)(&T[(c + 1) * 64 + y0 + 4]);
      *(float4*)&uf0[0] = *(const float4*)(&U[c * 132 + x0]);
      *(float4*)&uf1[0] = *(const float4*)(&U[(c + 1) * 132 + x0]);
#pragma unroll
      for (int jy = 0; jy < 8; ++jy)
#pragma unroll
        for (int jx = 0; jx < 4; ++jx) {
          Pa[jy][jx] += tf0[jy] * uf0[jx];
          Qa[jy][jx] += tf1[jy] * uf1[jx];
        }
    }
    {  // c = 60 (even -> P)
      float tf0[8], uf0[4];
      *(float4*)&tf0[0] = *(const float4*)(&T[60 * 64 + y0]);
      *(float4*)&tf0[4] = *(const float4*)(&T[60 * 64 + y0 + 4]);
      *(float4*)&uf0[0] = *(const float4*)(&U[60 * 132 + x0]);
#pragma unroll
      for (int jy = 0; jy < 8; ++jy)
#pragma unroll
        for (int jx = 0; jx < 4; ++jx) Pa[jy][jx] += tf0[jy] * uf0[jx];
    }
    const float bo_ = bias[o];
    float* op = out + (size_t)(b * 64 + o) * 16384;
#pragma unroll
    for (int jy = 0; jy < 8; ++jy) {
      float4 lo, hi;
      lo.x = Pa[jy][0] + Qa[jy][0] + bo_;
      lo.y = Pa[jy][1] + Qa[jy][1] + bo_;
      lo.z = Pa[jy][2] + Qa[jy][2] + bo_;
      lo.w = Pa[jy][3] + Qa[jy][3] + bo_;
      hi.x = Pa[jy][0] - Qa[jy][0] + bo_;
      hi.y = Pa[jy][1] - Qa[jy][1] + bo_;
      hi.z = Pa[jy][2] - Qa[jy][2] + bo_;
      hi.w = Pa[jy][3] - Qa[jy][3] + bo_;
      *(float4*)(op + (y0 + jy) * 128 + x0) = lo;
      *(float4*)(op + (y0 + jy + 64) * 128 + x0) = hi;
    }
  }
}

extern "C" void kernel_launch(void* const* d_in, const int* in_sizes, int n_in,
                              void* d_out, int out_size, void* d_ws, size_t ws_size,
                              hipStream_t stream) {
  (void)in_sizes; (void)n_in; (void)out_size; (void)ws_size;
  const float* x = (const float*)d_in[0];
  const float* w = (const float*)d_in[1];
  const float* bias = (const float*)d_in[2];
  float* out = (float*)d_out;

  unsigned* Wt = (unsigned*)d_ws;
  float* X2 = (float*)d_ws + 7745536;
  float* F = (float*)d_ws + 11618304;

  k0_what<<<976, 256, 0, stream>>>(w, Wt);
  k12_fwd<<<1024, 256, 0, stream>>>(x, X2);
  k3_mfma<<<946, 256, 0, stream>>>(X2, Wt, F);
  k45_out<<<1024, 256, 0, stream>>>(F, bias, out);
}

// Round 4
// 235.958 us; speedup vs baseline: 1.0243x; 1.0243x over previous
//
#include <hip/hip_runtime.h>

// FFTConvNet: out[b,o] = IFFT2( M · sum_i X^[(b+8)%16, i] · W^[(o+32)%64, i] ) + bias[o]
// fftshift(no axes) shifts ALL dims -> batch roll 8, Cout roll 32; Cin rolls cancel.
// Disk mask fy^2+fx^2<=900. Half-spectrum: fy(t) in [0,30] (31), fx in [-30,30] (61), f2 = fxp*31+t.
// k3 is an MFMA kernel: per freq, Out[16b x 64o] complex = A[16x128] * B[128x128] real-packed.
// k12 Cls geometry: row stride 70, plane stride 2244 (conflict-free; verified 6.55M -> 0).
// k0 thread map: o = ((tid>>5)<<3)|((tid>>2)&7), il = tid&3 -> store addr = base + (tid>>5)*512
//   + (tid&31): each 32-lane group writes 128B contiguous (fragment-order AND coalesced).
// WtB layout (16KB/freq, fragment-order): u32 idx = f2*4096 + (o>>3)*512 + (i>>4)*128
//                                                  + (((i>>2)&3)*8 + (o&7))*4 + (i&3)
// F layout [f2][16 b][128 col] f32 (col=2o re, 2o+1 im); k45 gathers strided (L2/L3-served).
// ws: WtB u32 [0, 7745536) ; X2 float [7745536, +3872768) ; F float [11618304, +3872768).

#define PI2_128 0.04908738521234052f  // 2*pi/128
#define NF 1891

typedef __attribute__((ext_vector_type(8))) short bf16x8;
typedef __attribute__((ext_vector_type(4))) float f32x4;

// fxp list ordered by class r=(fxp+2)&3 (= fx mod 4): c0(15), c1(15), c2(16), c3(15), 3 dummies.
__device__ const int k_flist[64] = {
    2, 6, 10, 14, 18, 22, 26, 30, 34, 38, 42, 46, 50, 54, 58,
    3, 7, 11, 15, 19, 23, 27, 31, 35, 39, 43, 47, 51, 55, 59,
    0, 4, 8, 12, 16, 20, 24, 28, 32, 36, 40, 44, 48, 52, 56, 60,
    1, 5, 9, 13, 17, 21, 25, 29, 33, 37, 41, 45, 49, 53, 57,
    0, 0, 0};

__device__ inline unsigned bf16_rne(float v) {
  unsigned u = __float_as_uint(v);
  return (u + 0x7FFFu + ((u >> 16) & 1u)) >> 16;
}

__device__ inline bf16x8 mk_bf16x8(unsigned a, unsigned b, unsigned c, unsigned d) {
  union { unsigned u[4]; bf16x8 v; } x;
  x.u[0] = a; x.u[1] = b; x.u[2] = c; x.u[3] = d;
  return x.v;
}

// ---------------- K0: W^ precompute (bf16), separable 3x3 twiddles ----------------
// Stores into MFMA-fragment order with a thread permutation that keeps stores coalesced.
__global__ __launch_bounds__(256) void k0_what(const float* __restrict__ w,
                                               unsigned* __restrict__ Wt) {
  const int tid = threadIdx.x;
  const int fxp = blockIdx.x >> 4;  // 0..60
  const int ig = blockIdx.x & 15;
  // Thread permutation: store address = frag_base + (tid>>5)*512 + (tid&31)  (coalesced).
  const int il = tid & 3;
  const int o = ((tid >> 5) << 3) | ((tid >> 2) & 7);
  const int i = ig * 4 + il;
  const int op = (o + 32) & 63;
  const float* wp = w + (size_t)(op * 64 + i) * 9;
  float w9[9];
#pragma unroll
  for (int k = 0; k < 9; ++k) w9[k] = wp[k];

  const float fx = (float)(fxp - 30);
  float sn, cs;
  __sincosf(fx * PI2_128, &sn, &cs);
  const float e1x = cs, e1y = -sn;
  const float e2x = e1x * e1x - e1y * e1y, e2y = 2.f * e1x * e1y;
  float rxr[3], rxi[3];
#pragma unroll
  for (int ky = 0; ky < 3; ++ky) {
    rxr[ky] = w9[ky * 3] + w9[ky * 3 + 1] * e1x + w9[ky * 3 + 2] * e2x;
    rxi[ky] = w9[ky * 3 + 1] * e1y + w9[ky * 3 + 2] * e2y;
  }
  float pyx = 1.f, pyy = 0.f;
  const float stx = 0.9987954562f, sty = -0.04906767433f;
  // fragment-order base: (o>>3)*512 + (i>>4)*128 + (((i>>2)&3)*8 + (o&7))*4 + (i&3)
  unsigned* Wb = Wt + (size_t)(fxp * 31) * 4096 + (o >> 3) * 512 + (i >> 4) * 128 +
                 (((i >> 2) & 3) * 8 + (o & 7)) * 4 + (i & 3);
  for (int fy = 0; fy < 31; ++fy) {
    float p2x = pyx * pyx - pyy * pyy, p2y = 2.f * pyx * pyy;
    float Wre = rxr[0] + (rxr[1] * pyx - rxi[1] * pyy) + (rxr[2] * p2x - rxi[2] * p2y);
    float Wim = rxi[0] + (rxr[1] * pyy + rxi[1] * pyx) + (rxr[2] * p2y + rxi[2] * p2x);
    Wb[(size_t)fy * 4096] = bf16_rne(Wre) | (bf16_rne(Wim) << 16);
    float nx = pyx * stx - pyy * sty;
    pyy = pyx * sty + pyy * stx;
    pyx = nx;
  }
}

// ---------------- K12: fused forward DFT (radix-4 folded both axes) ----------------
__global__ __launch_bounds__(256) void k12_fwd(const float* __restrict__ x,
                                               float* __restrict__ X2) {
  // Cls[r*2244 + x*70 + 2t(+1)]: 4 folded class-planes for phase B.
  // row stride 70 -> write banks (16g+6h): 2-way = free; plane stride 2244 (%32==4)
  // -> the 4 r-class reads per half-wave land on disjoint bank quads.
  __shared__ __align__(16) float Cls[8968];
  const int bi = blockIdx.x;
  const int tid = threadIdx.x;
  const float* img = x + (size_t)bi * 16384;

  // Phase A: y-DFT, radix-4 fold over y. Thread owns x in {xg,+32,+64,+96}, 4 freqs.
  {
    const int tg = tid >> 5;  // 0..7
    const int xg = tid & 31;
    const int t_[4] = {4 * tg, 4 * tg + 2, 2 * tg + 1, 2 * tg + 17};  // t=31 computed, discarded
    const float sgn = (tg & 1) ? 1.f : -1.f;  // (-i)^t for odd t: -i (t%4==1) / +i (t%4==3)
    float pc[4], ps[4], stc[4], sts[4];
#pragma unroll
    for (int f = 0; f < 4; ++f) {
      __sincosf((float)t_[f] * PI2_128, &sts[f], &stc[f]);
      pc[f] = 1.f;
      ps[f] = 0.f;
    }
    float ar_[4][4] = {{0.f}}, ai_[4][4] = {{0.f}};  // [freq][m]
    for (int y = 0; y < 32; ++y) {
      float v[4][4];
#pragma unroll
      for (int k = 0; k < 4; ++k)
#pragma unroll
        for (int m = 0; m < 4; ++m) v[k][m] = img[(y + 32 * k) * 128 + xg + 32 * m];
#pragma unroll
      for (int m = 0; m < 4; ++m) {
        float s = v[0][m] + v[2][m], d = v[0][m] - v[2][m];
        float s2 = v[1][m] + v[3][m], d2 = (v[1][m] - v[3][m]) * sgn;
        float a0 = s + s2, a1 = s - s2;
        ar_[0][m] += a0 * pc[0];
        ai_[0][m] -= a0 * ps[0];
        ar_[1][m] += a1 * pc[1];
        ai_[1][m] -= a1 * ps[1];
        ar_[2][m] += d * pc[2] + d2 * ps[2];
        ai_[2][m] += -d * ps[2] + d2 * pc[2];
        ar_[3][m] += d * pc[3] + d2 * ps[3];
        ai_[3][m] += -d * ps[3] + d2 * pc[3];
      }
#pragma unroll
      for (int f = 0; f < 4; ++f) {
        float c = pc[f], s = ps[f];
        pc[f] = c * stc[f] - s * sts[f];
        ps[f] = s * stc[f] + c * sts[f];
      }
    }
    // In-register x-butterfly (classes for phase B's fx fold), write 4 planes.
#pragma unroll
    for (int f = 0; f < 4; ++f) {
      int t = t_[f];
      float Ar = ar_[f][0] + ar_[f][2], Ai = ai_[f][0] + ai_[f][2];
      float Br = ar_[f][0] - ar_[f][2], Bi = ai_[f][0] - ai_[f][2];
      float Cr = ar_[f][1] + ar_[f][3], Ci = ai_[f][1] + ai_[f][3];
      float Dr = ar_[f][1] - ar_[f][3], Di = ai_[f][1] - ai_[f][3];
      float* base = Cls + xg * 70 + 2 * t;
      *(float2*)(base + 0 * 2244) = make_float2(Ar + Cr, Ai + Ci);  // r=0: A+C
      *(float2*)(base + 1 * 2244) = make_float2(Br + Di, Bi - Dr);  // r=1: B-iD
      *(float2*)(base + 2 * 2244) = make_float2(Ar - Cr, Ai - Ci);  // r=2: A-C
      *(float2*)(base + 3 * 2244) = make_float2(Br - Di, Bi + Dr);  // r=3: B+iD
    }
  }
  __syncthreads();

  // Phase B: x-DFT on folded planes (32 samples per freq) + disk mask.
  {
    const int tg2 = tid >> 5;  // t-quad: t = 4*tg2 + tt
    const int fxg = tid & 31;
    float accr[2][4] = {{0.f}}, acci[2][4] = {{0.f}};
    int fxp_[2], r_[2];
    float pc2[2], ps2[2], stc2[2], sts2[2];
#pragma unroll
    for (int u = 0; u < 2; ++u) {
      fxp_[u] = k_flist[2 * fxg + u];
      r_[u] = (fxp_[u] + 2) & 3;
      float fx = (float)(fxp_[u] - 30);
      __sincosf(fx * PI2_128, &sts2[u], &stc2[u]);
      pc2[u] = 1.f;
      ps2[u] = 0.f;
    }
    for (int xx = 0; xx < 32; ++xx) {
#pragma unroll
      for (int u = 0; u < 2; ++u) {
        const float* bp = Cls + r_[u] * 2244 + xx * 70 + 8 * tg2;
        float2 p0 = *(const float2*)(bp);
        float2 p1 = *(const float2*)(bp + 2);
        float2 p2 = *(const float2*)(bp + 4);
        float2 p3 = *(const float2*)(bp + 6);
        float zr[4] = {p0.x, p1.x, p2.x, p3.x};
        float zi[4] = {p0.y, p1.y, p2.y, p3.y};
        float c = pc2[u], s = ps2[u];
#pragma unroll
        for (int tt = 0; tt < 4; ++tt) {
          accr[u][tt] += zr[tt] * c + zi[tt] * s;
          acci[u][tt] += zi[tt] * c - zr[tt] * s;
        }
        pc2[u] = c * stc2[u] - s * sts2[u];
        ps2[u] = s * stc2[u] + c * sts2[u];
      }
    }
    float2* X2c = (float2*)X2 + (size_t)bi * NF;
#pragma unroll
    for (int u = 0; u < 2; ++u) {
      if (2 * fxg + u >= 61) continue;
      int fxp = fxp_[u], fx = fxp - 30;
#pragma unroll
      for (int tt = 0; tt < 4; ++tt) {
        int t = 4 * tg2 + tt;
        if (t >= 31) continue;
        bool keep = (t * t + fx * fx) <= 900;
        X2c[fxp * 31 + t] =
            keep ? make_float2(accr[u][tt], acci[u][tt]) : make_float2(0.f, 0.f);
      }
    }
  }
}

// ---------------- K3: per-frequency channel mix via MFMA (bf16, X split hi/lo) ----
// One wave = one (freq, N-half). 2 waves/freq, 4 waves/block -> 2 freqs/block.
// Zero LDS, zero barriers. Writes F[f2][b][col] (col = 2o + re/im).
__global__ __launch_bounds__(256) void k3_mfma(const float* __restrict__ X2,
                                               const unsigned* __restrict__ WtB,
                                               float* __restrict__ F) {
  // bijective XCD-chunked blockIdx swizzle (m204 form) for L2 locality of X gathers
  const int nwg = (int)gridDim.x;
  const int orig = (int)blockIdx.x;
  const int xcd = orig & 7;
  const int q = nwg >> 3, r = nwg & 7;
  const int blk = (xcd < r ? xcd * (q + 1) : r * (q + 1) + (xcd - r) * q) + (orig >> 3);

  const int tid = (int)threadIdx.x;
  const int wv = tid >> 6;
  const int g = blk * 4 + wv;
  const int f2 = g >> 1;
  if (f2 >= NF) return;
  const int half = g & 1;
  const int lane = tid & 63;
  const int m = lane & 15;   // A-row (output batch) == B-col-within-tile
  const int lg = lane >> 4;  // k lane-group
  const int bs = (m + 8) & 15;
  const int co = m & 1;      // re/im column parity

  // ---- A: gather X[bs][i] (i = ks*16 + lg*4 + t) for this freq; split hi/lo bf16 ----
  float2 xv[4][4];
  const float2* Xc = (const float2*)X2;
#pragma unroll
  for (int ks = 0; ks < 4; ++ks)
#pragma unroll
    for (int t = 0; t < 4; ++t)
      xv[ks][t] = Xc[(size_t)(bs * 64 + ks * 16 + lg * 4 + t) * NF + f2];

  unsigned ahi[4][4], alo[4][4];
#pragma unroll
  for (int ks = 0; ks < 4; ++ks) {
#pragma unroll
    for (int t = 0; t < 4; ++t) {
      float xr = xv[ks][t].x, xi = xv[ks][t].y;
      unsigned hr = bf16_rne(xr), hi2 = bf16_rne(xi);
      float lr = xr - __uint_as_float(hr << 16);
      float li = xi - __uint_as_float(hi2 << 16);
      ahi[ks][t] = hr | (hi2 << 16);
      alo[ks][t] = bf16_rne(lr) | (bf16_rne(li) << 16);
    }
  }

  // ---- GEMM: acc[nt] over 4 N-tiles (this wave's N-half), K = 4 steps of 32 ----
  f32x4 acc[4];
#pragma unroll
  for (int nt = 0; nt < 4; ++nt) acc[nt] = {0.f, 0.f, 0.f, 0.f};

  const unsigned* Wb =
      WtB + (size_t)f2 * 4096 + half * 2048 + (lg * 8 + (m >> 1)) * 4;
#pragma unroll
  for (int ks = 0; ks < 4; ++ks) {
    bf16x8 bfr[4];
#pragma unroll
    for (int nt = 0; nt < 4; ++nt) {
      uint4 wq = *(const uint4*)(Wb + nt * 512 + ks * 128);
      unsigned b0, b1, b2, b3;
      if (co) {  // odd col: (Wi, Wr) = rot16(w)
        b0 = (wq.x >> 16) | (wq.x << 16);
        b1 = (wq.y >> 16) | (wq.y << 16);
        b2 = (wq.z >> 16) | (wq.z << 16);
        b3 = (wq.w >> 16) | (wq.w << 16);
      } else {   // even col: (Wr, -Wi) = w ^ signbit(hi)
        b0 = wq.x ^ 0x80000000u;
        b1 = wq.y ^ 0x80000000u;
        b2 = wq.z ^ 0x80000000u;
        b3 = wq.w ^ 0x80000000u;
      }
      bfr[nt] = mk_bf16x8(b0, b1, b2, b3);
    }
    bf16x8 ah = mk_bf16x8(ahi[ks][0], ahi[ks][1], ahi[ks][2], ahi[ks][3]);
    bf16x8 al = mk_bf16x8(alo[ks][0], alo[ks][1], alo[ks][2], alo[ks][3]);
#pragma unroll
    for (int nt = 0; nt < 4; ++nt)
      acc[nt] = __builtin_amdgcn_mfma_f32_16x16x32_bf16(ah, bfr[nt], acc[nt], 0, 0, 0);
#pragma unroll
    for (int nt = 0; nt < 4; ++nt)
      acc[nt] = __builtin_amdgcn_mfma_f32_16x16x32_bf16(al, bfr[nt], acc[nt], 0, 0, 0);
  }

  // ---- store: D row = lg*4 + rr (batch), col = half*64 + nt*16 + m ----
  float* Fo = F + (size_t)f2 * 2048 + half * 64 + m;
#pragma unroll
  for (int nt = 0; nt < 4; ++nt)
#pragma unroll
    for (int rr = 0; rr < 4; ++rr)
      Fo[(lg * 4 + rr) * 128 + nt * 16] = acc[nt][rr];
}

// ---------------- K45: inverse (radix-4 fold in x, parity fold in y) + bias ----------------
__global__ __launch_bounds__(256) void k45_out(const float* __restrict__ F,
                                               const float* __restrict__ bias,
                                               float* __restrict__ out) {
  __shared__ __align__(16) float2 tw[128];  // e^{+2pi i m/128}
  __shared__ __align__(16) float U[61 * 132];
  __shared__ __align__(16) float TF[3904];  // union: Fl (phase<=1), then T
  const int b = blockIdx.x >> 6;
  const int o = blockIdx.x & 63;
  const int tid = threadIdx.x;
  float2* Fl = (float2*)TF;
  // F layout is [f2][16 b][64 o] float2 -> gather with stride 1024 float2s.
  const float2* Fc = (const float2*)F + (size_t)(b * 64 + o);
  if (tid < 128) {
    float sv, cv;
    __sincosf((float)tid * PI2_128, &sv, &cv);
    tw[tid] = make_float2(cv, sv);
  }
  for (int j = tid; j < NF; j += 256) Fl[j] = Fc[(size_t)j * 1024];
  __syncthreads();

  // Phase 1: inverse-x with output fold H(x+32k) = sum_r i^{rk} S_r
  {
    const int fy = tid & 31;
    const int xg = tid >> 3 >> 2;  // tid>>5: 0..7
    if (fy < 31) {
      float Sr[4][4] = {{0.f}}, Si[4][4] = {{0.f}};  // [r][j]
      float pr[4], pi[4], cr[4], ci[4];
#pragma unroll
      for (int j = 0; j < 4; ++j) {
        int xj = 4 * xg + j;
        float2 st = tw[xj];
        cr[j] = st.x;
        ci[j] = st.y;
        float2 p0 = tw[(-30 * xj) & 127];
        pr[j] = p0.x;
        pi[j] = p0.y;
      }
      const float2* Frow = Fl + fy;
      for (int f4 = 0; f4 < 60; f4 += 4) {
#pragma unroll
        for (int ss = 0; ss < 4; ++ss) {
          const int r = (ss + 2) & 3;  // fxp class pattern 2,3,0,1
          float2 fv = Frow[(f4 + ss) * 31];
#pragma unroll
          for (int j = 0; j < 4; ++j) {
            Sr[r][j] += fv.x * pr[j] - fv.y * pi[j];
            Si[r][j] += fv.x * pi[j] + fv.y * pr[j];
            float np = pr[j] * cr[j] - pi[j] * ci[j];
            pi[j] = pi[j] * cr[j] + pr[j] * ci[j];
            pr[j] = np;
          }
        }
      }
      {  // fxp = 60, class 2
        float2 fv = Frow[60 * 31];
#pragma unroll
        for (int j = 0; j < 4; ++j) {
          Sr[2][j] += fv.x * pr[j] - fv.y * pi[j];
          Si[2][j] += fv.x * pi[j] + fv.y * pr[j];
        }
      }
#pragma unroll
      for (int j = 0; j < 4; ++j) {
        int xj = 4 * xg + j;
        float Er = Sr[0][j] + Sr[2][j], Ei = Si[0][j] + Si[2][j];
        float Fr = Sr[0][j] - Sr[2][j], Fi = Si[0][j] - Si[2][j];
        float Gr = Sr[1][j] + Sr[3][j], Gi = Si[1][j] + Si[3][j];
        float Hr = Sr[1][j] - Sr[3][j], Hi = Si[1][j] - Si[3][j];
        U[fy * 132 + xj] = Er + Gr;
        U[fy * 132 + xj + 32] = Fr - Hi;   // F4 + iH
        U[fy * 132 + xj + 64] = Er - Gr;
        U[fy * 132 + xj + 96] = Fr + Hi;   // F4 - iH
        if (fy >= 1) {
          U[(30 + fy) * 132 + xj] = Ei + Gi;
          U[(30 + fy) * 132 + xj + 32] = Fi + Hr;
          U[(30 + fy) * 132 + xj + 64] = Ei - Gi;
          U[(30 + fy) * 132 + xj + 96] = Fi - Hr;
        }
      }
    }
  }
  __syncthreads();
  // Build T[c][y] (y<64) over Fl's dead storage.
  {
    const float sc1 = 1.f / 16384.f;
    float* T = TF;
    for (int j = tid; j < 61 * 64; j += 256) {
      int c = j >> 6, y = j & 63;
      float val;
      if (c == 0) val = sc1;
      else if (c <= 30) val = 2.f * sc1 * tw[(c * y) & 127].x;
      else val = -2.f * sc1 * tw[((c - 30) * y) & 127].y;
      T[j] = val;
    }
  }
  __syncthreads();
  // Phase 2: inverse-y with parity fold (even c -> P, odd c -> Q); out[y]=P+Q, out[y+64]=P-Q
  {
    const float* T = TF;
    const int yg = tid >> 5;
    const int xg = tid & 31;
    const int y0 = yg * 8, x0 = xg * 4;
    float Pa[8][4] = {{0.f}}, Qa[8][4] = {{0.f}};
    for (int c = 0; c < 60; c += 2) {
      float tf0[8], tf1[8], uf0[4], uf1[4];
      *(float4*)&tf0[0] = *(const float4*)(&T[c * 64 + y0]);
      *(float4*)&tf0[4] = *(const float4*)(&T[c * 64 + y0 + 4]);
      *(float4*)&tf1[0] = *(const float4*)(&T[(c + 1) * 64 + y0]);
      *(float4*)&tf1[4] = *(const float4*)(&T[(c + 1) * 64 + y0 + 4]);
      *(float4*)&uf0[0] = *(const float4*)(&U[c * 132 + x0]);
      *(float4*)&uf1[0] = *(const float4*)(&U[(c + 1) * 132 + x0]);
#pragma unroll
      for (int jy = 0; jy < 8; ++jy)
#pragma unroll
        for (int jx = 0; jx < 4; ++jx) {
          Pa[jy][jx] += tf0[jy] * uf0[jx];
          Qa[jy][jx] += tf1[jy] * uf1[jx];
        }
    }
    {  // c = 60 (even -> P)
      float tf0[8], uf0[4];
      *(float4*)&tf0[0] = *(const float4*)(&T[60 * 64 + y0]);
      *(float4*)&tf0[4] = *(const float4*)(&T[60 * 64 + y0 + 4]);
      *(float4*)&uf0[0] = *(const float4*)(&U[60 * 132 + x0]);
#pragma unroll
      for (int jy = 0; jy < 8; ++jy)
#pragma unroll
        for (int jx = 0; jx < 4; ++jx) Pa[jy][jx] += tf0[jy] * uf0[jx];
    }
    const float bo_ = bias[o];
    float* op = out + (size_t)(b * 64 + o) * 16384;
#pragma unroll
    for (int jy = 0; jy < 8; ++jy) {
      float4 lo, hi;
      lo.x = Pa[jy][0] + Qa[jy][0] + bo_;
      lo.y = Pa[jy][1] + Qa[jy][1] + bo_;
      lo.z = Pa[jy][2] + Qa[jy][2] + bo_;
      lo.w = Pa[jy][3] + Qa[jy][3] + bo_;
      hi.x = Pa[jy][0] - Qa[jy][0] + bo_;
      hi.y = Pa[jy][1] - Qa[jy][1] + bo_;
      hi.z = Pa[jy][2] - Qa[jy][2] + bo_;
      hi.w = Pa[jy][3] - Qa[jy][3] + bo_;
      *(float4*)(op + (y0 + jy) * 128 + x0) = lo;
      *(float4*)(op + (y0 + jy + 64) * 128 + x0) = hi;
    }
  }
}

extern "C" void kernel_launch(void* const* d_in, const int* in_sizes, int n_in,
                              void* d_out, int out_size, void* d_ws, size_t ws_size,
                              hipStream_t stream) {
  (void)in_sizes; (void)n_in; (void)out_size; (void)ws_size;
  const float* x = (const float*)d_in[0];
  const float* w = (const float*)d_in[1];
  const float* bias = (const float*)d_in[2];
  float* out = (float*)d_out;

  unsigned* Wt = (unsigned*)d_ws;
  float* X2 = (float*)d_ws + 7745536;
  float* F = (float*)d_ws + 11618304;

  k0_what<<<976, 256, 0, stream>>>(w, Wt);
  k12_fwd<<<1024, 256, 0, stream>>>(x, X2);
  k3_mfma<<<946, 256, 0, stream>>>(X2, Wt, F);
  k45_out<<<1024, 256, 0, stream>>>(F, bias, out);
}

// Round 5
// 226.276 us; speedup vs baseline: 1.0682x; 1.0428x over previous
//
#include <hip/hip_runtime.h>

// FFTConvNet: out[b,o] = IFFT2( M · sum_i X^[(b+8)%16, i] · W^[(o+32)%64, i] ) + bias[o]
// fftshift(no axes) shifts ALL dims -> batch roll 8, Cout roll 32; Cin rolls cancel.
// Disk mask fy^2+fx^2<=900. Half-spectrum: fy(t) in [0,30] (31), fx in [-30,30] (61), f2 = fxp*31+t.
// Pipeline: k0 (W^ bf16, frag-order) ; k12 (fwd DFT -> X2[bi][f2]) ; ktx (X2 -> X2T[f2][i*16+b]) ;
//   k3 (MFMA mix, reads X2T coalesced, writes F[f2][b][col] IN-PLACE over X2T, barrier-protected) ;
//   ktf (F -> FT[bo][f2], aliases dead X2) ; k45 (inverse, contiguous FT rows).
// ws (62 MB, unchanged): WtB u32 [0, 7745536) ; A = X2 / FT float [7745536, +3872768) ;
//                        B = X2T / F float [11618304, +3872768).

#define PI2_128 0.04908738521234052f  // 2*pi/128
#define NF 1891

typedef __attribute__((ext_vector_type(8))) short bf16x8;
typedef __attribute__((ext_vector_type(4))) float f32x4;

// fxp list ordered by class r=(fxp+2)&3 (= fx mod 4): c0(15), c1(15), c2(16), c3(15), 3 dummies.
__device__ const int k_flist[64] = {
    2, 6, 10, 14, 18, 22, 26, 30, 34, 38, 42, 46, 50, 54, 58,
    3, 7, 11, 15, 19, 23, 27, 31, 35, 39, 43, 47, 51, 55, 59,
    0, 4, 8, 12, 16, 20, 24, 28, 32, 36, 40, 44, 48, 52, 56, 60,
    1, 5, 9, 13, 17, 21, 25, 29, 33, 37, 41, 45, 49, 53, 57,
    0, 0, 0};

__device__ inline unsigned bf16_rne(float v) {
  unsigned u = __float_as_uint(v);
  return (u + 0x7FFFu + ((u >> 16) & 1u)) >> 16;
}

__device__ inline bf16x8 mk_bf16x8(unsigned a, unsigned b, unsigned c, unsigned d) {
  union { unsigned u[4]; bf16x8 v; } x;
  x.u[0] = a; x.u[1] = b; x.u[2] = c; x.u[3] = d;
  return x.v;
}

// ---------------- K0: W^ precompute (bf16), separable 3x3 twiddles ----------------
__global__ __launch_bounds__(256) void k0_what(const float* __restrict__ w,
                                               unsigned* __restrict__ Wt) {
  const int tid = threadIdx.x;
  const int fxp = blockIdx.x >> 4;  // 0..60
  const int ig = blockIdx.x & 15;
  // Thread permutation: store address = frag_base + (tid>>5)*512 + (tid&31)  (coalesced).
  const int il = tid & 3;
  const int o = ((tid >> 5) << 3) | ((tid >> 2) & 7);
  const int i = ig * 4 + il;
  const int op = (o + 32) & 63;
  const float* wp = w + (size_t)(op * 64 + i) * 9;
  float w9[9];
#pragma unroll
  for (int k = 0; k < 9; ++k) w9[k] = wp[k];

  const float fx = (float)(fxp - 30);
  float sn, cs;
  __sincosf(fx * PI2_128, &sn, &cs);
  const float e1x = cs, e1y = -sn;
  const float e2x = e1x * e1x - e1y * e1y, e2y = 2.f * e1x * e1y;
  float rxr[3], rxi[3];
#pragma unroll
  for (int ky = 0; ky < 3; ++ky) {
    rxr[ky] = w9[ky * 3] + w9[ky * 3 + 1] * e1x + w9[ky * 3 + 2] * e2x;
    rxi[ky] = w9[ky * 3 + 1] * e1y + w9[ky * 3 + 2] * e2y;
  }
  float pyx = 1.f, pyy = 0.f;
  const float stx = 0.9987954562f, sty = -0.04906767433f;
  unsigned* Wb = Wt + (size_t)(fxp * 31) * 4096 + (o >> 3) * 512 + (i >> 4) * 128 +
                 (((i >> 2) & 3) * 8 + (o & 7)) * 4 + (i & 3);
  for (int fy = 0; fy < 31; ++fy) {
    float p2x = pyx * pyx - pyy * pyy, p2y = 2.f * pyx * pyy;
    float Wre = rxr[0] + (rxr[1] * pyx - rxi[1] * pyy) + (rxr[2] * p2x - rxi[2] * p2y);
    float Wim = rxi[0] + (rxr[1] * pyy + rxi[1] * pyx) + (rxr[2] * p2y + rxi[2] * p2x);
    Wb[(size_t)fy * 4096] = bf16_rne(Wre) | (bf16_rne(Wim) << 16);
    float nx = pyx * stx - pyy * sty;
    pyy = pyx * sty + pyy * stx;
    pyx = nx;
  }
}

// ---------------- K12: fused forward DFT (radix-4 folded both axes) ----------------
__global__ __launch_bounds__(256) void k12_fwd(const float* __restrict__ x,
                                               float* __restrict__ X2) {
  __shared__ __align__(16) float Cls[8968];
  const int bi = blockIdx.x;
  const int tid = threadIdx.x;
  const float* img = x + (size_t)bi * 16384;

  // Phase A: y-DFT, radix-4 fold over y. Thread owns x in {xg,+32,+64,+96}, 4 freqs.
  {
    const int tg = tid >> 5;  // 0..7
    const int xg = tid & 31;
    const int t_[4] = {4 * tg, 4 * tg + 2, 2 * tg + 1, 2 * tg + 17};  // t=31 computed, discarded
    const float sgn = (tg & 1) ? 1.f : -1.f;
    float pc[4], ps[4], stc[4], sts[4];
#pragma unroll
    for (int f = 0; f < 4; ++f) {
      __sincosf((float)t_[f] * PI2_128, &sts[f], &stc[f]);
      pc[f] = 1.f;
      ps[f] = 0.f;
    }
    float ar_[4][4] = {{0.f}}, ai_[4][4] = {{0.f}};  // [freq][m]
    for (int y = 0; y < 32; ++y) {
      float v[4][4];
#pragma unroll
      for (int k = 0; k < 4; ++k)
#pragma unroll
        for (int m = 0; m < 4; ++m) v[k][m] = img[(y + 32 * k) * 128 + xg + 32 * m];
#pragma unroll
      for (int m = 0; m < 4; ++m) {
        float s = v[0][m] + v[2][m], d = v[0][m] - v[2][m];
        float s2 = v[1][m] + v[3][m], d2 = (v[1][m] - v[3][m]) * sgn;
        float a0 = s + s2, a1 = s - s2;
        ar_[0][m] += a0 * pc[0];
        ai_[0][m] -= a0 * ps[0];
        ar_[1][m] += a1 * pc[1];
        ai_[1][m] -= a1 * ps[1];
        ar_[2][m] += d * pc[2] + d2 * ps[2];
        ai_[2][m] += -d * ps[2] + d2 * pc[2];
        ar_[3][m] += d * pc[3] + d2 * ps[3];
        ai_[3][m] += -d * ps[3] + d2 * pc[3];
      }
#pragma unroll
      for (int f = 0; f < 4; ++f) {
        float c = pc[f], s = ps[f];
        pc[f] = c * stc[f] - s * sts[f];
        ps[f] = s * stc[f] + c * sts[f];
      }
    }
#pragma unroll
    for (int f = 0; f < 4; ++f) {
      int t = t_[f];
      float Ar = ar_[f][0] + ar_[f][2], Ai = ai_[f][0] + ai_[f][2];
      float Br = ar_[f][0] - ar_[f][2], Bi = ai_[f][0] - ai_[f][2];
      float Cr = ar_[f][1] + ar_[f][3], Ci = ai_[f][1] + ai_[f][3];
      float Dr = ar_[f][1] - ar_[f][3], Di = ai_[f][1] - ai_[f][3];
      float* base = Cls + xg * 70 + 2 * t;
      *(float2*)(base + 0 * 2244) = make_float2(Ar + Cr, Ai + Ci);  // r=0: A+C
      *(float2*)(base + 1 * 2244) = make_float2(Br + Di, Bi - Dr);  // r=1: B-iD
      *(float2*)(base + 2 * 2244) = make_float2(Ar - Cr, Ai - Ci);  // r=2: A-C
      *(float2*)(base + 3 * 2244) = make_float2(Br - Di, Bi + Dr);  // r=3: B+iD
    }
  }
  __syncthreads();

  // Phase B: x-DFT on folded planes (32 samples per freq) + disk mask.
  {
    const int tg2 = tid >> 5;
    const int fxg = tid & 31;
    float accr[2][4] = {{0.f}}, acci[2][4] = {{0.f}};
    int fxp_[2], r_[2];
    float pc2[2], ps2[2], stc2[2], sts2[2];
#pragma unroll
    for (int u = 0; u < 2; ++u) {
      fxp_[u] = k_flist[2 * fxg + u];
      r_[u] = (fxp_[u] + 2) & 3;
      float fx = (float)(fxp_[u] - 30);
      __sincosf(fx * PI2_128, &sts2[u], &stc2[u]);
      pc2[u] = 1.f;
      ps2[u] = 0.f;
    }
    for (int xx = 0; xx < 32; ++xx) {
#pragma unroll
      for (int u = 0; u < 2; ++u) {
        const float* bp = Cls + r_[u] * 2244 + xx * 70 + 8 * tg2;
        float2 p0 = *(const float2*)(bp);
        float2 p1 = *(const float2*)(bp + 2);
        float2 p2 = *(const float2*)(bp + 4);
        float2 p3 = *(const float2*)(bp + 6);
        float zr[4] = {p0.x, p1.x, p2.x, p3.x};
        float zi[4] = {p0.y, p1.y, p2.y, p3.y};
        float c = pc2[u], s = ps2[u];
#pragma unroll
        for (int tt = 0; tt < 4; ++tt) {
          accr[u][tt] += zr[tt] * c + zi[tt] * s;
          acci[u][tt] += zi[tt] * c - zr[tt] * s;
        }
        pc2[u] = c * stc2[u] - s * sts2[u];
        ps2[u] = s * stc2[u] + c * sts2[u];
      }
    }
    float2* X2c = (float2*)X2 + (size_t)bi * NF;
#pragma unroll
    for (int u = 0; u < 2; ++u) {
      if (2 * fxg + u >= 61) continue;
      int fxp = fxp_[u], fx = fxp - 30;
#pragma unroll
      for (int tt = 0; tt < 4; ++tt) {
        int t = 4 * tg2 + tt;
        if (t >= 31) continue;
        bool keep = (t * t + fx * fx) <= 900;
        X2c[fxp * 31 + t] =
            keep ? make_float2(accr[u][tt], acci[u][tt]) : make_float2(0.f, 0.f);
      }
    }
  }
}

// ---------------- KTX: X2[bi][f2] -> X2T[f2][i*16+b]  (64x64 float2 LDS tiles) ------
__global__ __launch_bounds__(256) void ktx(const float2* __restrict__ X2,
                                           float2* __restrict__ X2T) {
  __shared__ __align__(16) float2 Ld[4096];
  const int tid = threadIdx.x;
  const int tf = blockIdx.x % 30;  // f2 tile
  const int tc = blockIdx.x / 30;  // out-col tile: i0 = tc*4
  const int f2_0 = tf * 64;
  const int lo = tid & 63, hi = tid >> 6;
#pragma unroll
  for (int k = 0; k < 16; ++k) {
    int c = k * 4 + hi;  // local out-col: c = (i-i0)*16 + b
    int bi = (c & 15) * 64 + tc * 4 + (c >> 4);
    int f2 = f2_0 + lo;
    float2 v = (f2 < NF) ? X2[(size_t)bi * NF + f2] : make_float2(0.f, 0.f);
    Ld[(c << 6) | (lo ^ c)] = v;  // XOR-swizzled: conflict-free both phases
  }
  __syncthreads();
#pragma unroll
  for (int k = 0; k < 16; ++k) {
    int fr = k * 4 + hi;
    int f2 = f2_0 + fr;
    if (f2 < NF) X2T[(size_t)f2 * 1024 + tc * 64 + lo] = Ld[(lo << 6) | (fr ^ lo)];
  }
}

// ---------------- K3: per-frequency channel mix via MFMA (bf16, X split hi/lo) ----
// Reads X2T[f2][i*16+b] (coalesced 128B segments); writes F[f2][b][col] IN-PLACE over
// X2T (same rows) -- all 4 waves gather before the barrier, stores after. No __restrict
// on the aliased pointers.
__global__ __launch_bounds__(256) void k3_mfma(const float* X2T,
                                               const unsigned* __restrict__ WtB,
                                               float* F) {
  // bijective XCD-chunked blockIdx swizzle (m204 form)
  const int nwg = (int)gridDim.x;
  const int orig = (int)blockIdx.x;
  const int xcd = orig & 7;
  const int q = nwg >> 3, r = nwg & 7;
  const int blk = (xcd < r ? xcd * (q + 1) : r * (q + 1) + (xcd - r) * q) + (orig >> 3);

  const int tid = (int)threadIdx.x;
  const int wv = tid >> 6;
  const int g = blk * 4 + wv;
  const int f2v = g >> 1;
  const bool valid = f2v < NF;
  const int f2 = valid ? f2v : NF - 1;  // clamp keeps reads in the block's own rows
  const int half = g & 1;
  const int lane = tid & 63;
  const int m = lane & 15;   // A-row (output batch) == B-col-within-tile
  const int lg = lane >> 4;  // k lane-group
  const int bs = (m + 8) & 15;
  const int co = m & 1;      // re/im column parity

  // ---- A: gather X2T row f2 (coalesced); i = ks*16 + lg*4 + t ----
  float2 xv[4][4];
  const float2* Xc = (const float2*)X2T;
#pragma unroll
  for (int ks = 0; ks < 4; ++ks)
#pragma unroll
    for (int t = 0; t < 4; ++t)
      xv[ks][t] = Xc[(size_t)f2 * 1024 + (ks * 16 + lg * 4 + t) * 16 + bs];

  __syncthreads();  // all waves done reading their rows before any in-place store

  unsigned ahi[4][4], alo[4][4];
#pragma unroll
  for (int ks = 0; ks < 4; ++ks) {
#pragma unroll
    for (int t = 0; t < 4; ++t) {
      float xr = xv[ks][t].x, xi = xv[ks][t].y;
      unsigned hr = bf16_rne(xr), hi2 = bf16_rne(xi);
      float lr = xr - __uint_as_float(hr << 16);
      float li = xi - __uint_as_float(hi2 << 16);
      ahi[ks][t] = hr | (hi2 << 16);
      alo[ks][t] = bf16_rne(lr) | (bf16_rne(li) << 16);
    }
  }

  f32x4 acc[4];
#pragma unroll
  for (int nt = 0; nt < 4; ++nt) acc[nt] = {0.f, 0.f, 0.f, 0.f};

  const unsigned* Wb =
      WtB + (size_t)f2 * 4096 + half * 2048 + (lg * 8 + (m >> 1)) * 4;
#pragma unroll
  for (int ks = 0; ks < 4; ++ks) {
    bf16x8 bfr[4];
#pragma unroll
    for (int nt = 0; nt < 4; ++nt) {
      uint4 wq = *(const uint4*)(Wb + nt * 512 + ks * 128);
      unsigned b0, b1, b2, b3;
      if (co) {  // odd col: (Wi, Wr) = rot16(w)
        b0 = (wq.x >> 16) | (wq.x << 16);
        b1 = (wq.y >> 16) | (wq.y << 16);
        b2 = (wq.z >> 16) | (wq.z << 16);
        b3 = (wq.w >> 16) | (wq.w << 16);
      } else {   // even col: (Wr, -Wi) = w ^ signbit(hi)
        b0 = wq.x ^ 0x80000000u;
        b1 = wq.y ^ 0x80000000u;
        b2 = wq.z ^ 0x80000000u;
        b3 = wq.w ^ 0x80000000u;
      }
      bfr[nt] = mk_bf16x8(b0, b1, b2, b3);
    }
    bf16x8 ah = mk_bf16x8(ahi[ks][0], ahi[ks][1], ahi[ks][2], ahi[ks][3]);
    bf16x8 al = mk_bf16x8(alo[ks][0], alo[ks][1], alo[ks][2], alo[ks][3]);
#pragma unroll
    for (int nt = 0; nt < 4; ++nt)
      acc[nt] = __builtin_amdgcn_mfma_f32_16x16x32_bf16(ah, bfr[nt], acc[nt], 0, 0, 0);
#pragma unroll
    for (int nt = 0; nt < 4; ++nt)
      acc[nt] = __builtin_amdgcn_mfma_f32_16x16x32_bf16(al, bfr[nt], acc[nt], 0, 0, 0);
  }

  if (valid) {
    float* Fo = F + (size_t)f2 * 2048 + half * 64 + m;
#pragma unroll
    for (int nt = 0; nt < 4; ++nt)
#pragma unroll
      for (int rr = 0; rr < 4; ++rr)
        Fo[(lg * 4 + rr) * 128 + nt * 16] = acc[nt][rr];
  }
}

// ---------------- KTF: F[f2][bo] -> FT[bo][f2]  (64x64 float2 LDS tiles) -----------
__global__ __launch_bounds__(256) void ktf(const float2* __restrict__ F2,
                                           float2* __restrict__ FT) {
  __shared__ __align__(16) float2 Ld[4096];
  const int tid = threadIdx.x;
  const int tf = blockIdx.x % 30;
  const int tc = blockIdx.x / 30;
  const int f2_0 = tf * 64, c0 = tc * 64;
  const int lo = tid & 63, hi = tid >> 6;
#pragma unroll
  for (int k = 0; k < 16; ++k) {
    int fr = k * 4 + hi;
    int f2 = f2_0 + fr;
    float2 v = (f2 < NF) ? F2[(size_t)f2 * 1024 + c0 + lo] : make_float2(0.f, 0.f);
    Ld[(fr << 6) | (lo ^ fr)] = v;
  }
  __syncthreads();
#pragma unroll
  for (int k = 0; k < 16; ++k) {
    int cc = k * 4 + hi;
    int f2 = f2_0 + lo;
    if (f2 < NF) FT[(size_t)(c0 + cc) * NF + f2] = Ld[(lo << 6) | (cc ^ lo)];
  }
}

// ---------------- K45: inverse (radix-4 fold in x, parity fold in y) + bias ----------------
__global__ __launch_bounds__(256) void k45_out(const float* __restrict__ FT,
                                               const float* __restrict__ bias,
                                               float* __restrict__ out) {
  __shared__ __align__(16) float2 tw[128];  // e^{+2pi i m/128}
  __shared__ __align__(16) float U[61 * 132];
  __shared__ __align__(16) float TF[3904];  // union: Fl (phase<=1), then T
  const int b = blockIdx.x >> 6;
  const int o = blockIdx.x & 63;
  const int tid = threadIdx.x;
  float2* Fl = (float2*)TF;
  // FT layout [bo][NF] -> contiguous row load.
  const float2* Fc = (const float2*)FT + (size_t)(b * 64 + o) * NF;
  if (tid < 128) {
    float sv, cv;
    __sincosf((float)tid * PI2_128, &sv, &cv);
    tw[tid] = make_float2(cv, sv);
  }
  for (int j = tid; j < NF; j += 256) Fl[j] = Fc[j];
  __syncthreads();

  // Phase 1: inverse-x with output fold H(x+32k) = sum_r i^{rk} S_r
  {
    const int fy = tid & 31;
    const int xg = tid >> 3 >> 2;  // tid>>5: 0..7
    if (fy < 31) {
      float Sr[4][4] = {{0.f}}, Si[4][4] = {{0.f}};  // [r][j]
      float pr[4], pi[4], cr[4], ci[4];
#pragma unroll
      for (int j = 0; j < 4; ++j) {
        int xj = 4 * xg + j;
        float2 st = tw[xj];
        cr[j] = st.x;
        ci[j] = st.y;
        float2 p0 = tw[(-30 * xj) & 127];
        pr[j] = p0.x;
        pi[j] = p0.y;
      }
      const float2* Frow = Fl + fy;
      for (int f4 = 0; f4 < 60; f4 += 4) {
#pragma unroll
        for (int ss = 0; ss < 4; ++ss) {
          const int r = (ss + 2) & 3;  // fxp class pattern 2,3,0,1
          float2 fv = Frow[(f4 + ss) * 31];
#pragma unroll
          for (int j = 0; j < 4; ++j) {
            Sr[r][j] += fv.x * pr[j] - fv.y * pi[j];
            Si[r][j] += fv.x * pi[j] + fv.y * pr[j];
            float np = pr[j] * cr[j] - pi[j] * ci[j];
            pi[j] = pi[j] * cr[j] + pr[j] * ci[j];
            pr[j] = np;
          }
        }
      }
      {  // fxp = 60, class 2
        float2 fv = Frow[60 * 31];
#pragma unroll
        for (int j = 0; j < 4; ++j) {
          Sr[2][j] += fv.x * pr[j] - fv.y * pi[j];
          Si[2][j] += fv.x * pi[j] + fv.y * pr[j];
        }
      }
#pragma unroll
      for (int j = 0; j < 4; ++j) {
        int xj = 4 * xg + j;
        float Er = Sr[0][j] + Sr[2][j], Ei = Si[0][j] + Si[2][j];
        float Fr = Sr[0][j] - Sr[2][j], Fi = Si[0][j] - Si[2][j];
        float Gr = Sr[1][j] + Sr[3][j], Gi = Si[1][j] + Si[3][j];
        float Hr = Sr[1][j] - Sr[3][j], Hi = Si[1][j] - Si[3][j];
        U[fy * 132 + xj] = Er + Gr;
        U[fy * 132 + xj + 32] = Fr - Hi;   // F4 + iH
        U[fy * 132 + xj + 64] = Er - Gr;
        U[fy * 132 + xj + 96] = Fr + Hi;   // F4 - iH
        if (fy >= 1) {
          U[(30 + fy) * 132 + xj] = Ei + Gi;
          U[(30 + fy) * 132 + xj + 32] = Fi + Hr;
          U[(30 + fy) * 132 + xj + 64] = Ei - Gi;
          U[(30 + fy) * 132 + xj + 96] = Fi - Hr;
        }
      }
    }
  }
  __syncthreads();
  // Build T[c][y] (y<64) over Fl's dead storage.
  {
    const float sc1 = 1.f / 16384.f;
    float* T = TF;
    for (int j = tid; j < 61 * 64; j += 256) {
      int c = j >> 6, y = j & 63;
      float val;
      if (c == 0) val = sc1;
      else if (c <= 30) val = 2.f * sc1 * tw[(c * y) & 127].x;
      else val = -2.f * sc1 * tw[((c - 30) * y) & 127].y;
      T[j] = val;
    }
  }
  __syncthreads();
  // Phase 2: inverse-y with parity fold (even c -> P, odd c -> Q); out[y]=P+Q, out[y+64]=P-Q
  {
    const float* T = TF;
    const int yg = tid >> 5;
    const int xg = tid & 31;
    const int y0 = yg * 8, x0 = xg * 4;
    float Pa[8][4] = {{0.f}}, Qa[8][4] = {{0.f}};
    for (int c = 0; c < 60; c += 2) {
      float tf0[8], tf1[8], uf0[4], uf1[4];
      *(float4*)&tf0[0] = *(const float4*)(&T[c * 64 + y0]);
      *(float4*)&tf0[4] = *(const float4*)(&T[c * 64 + y0 + 4]);
      *(float4*)&tf1[0] = *(const float4*)(&T[(c + 1) * 64 + y0]);
      *(float4*)&tf1[4] = *(const float4*)(&T[(c + 1) * 64 + y0 + 4]);
      *(float4*)&uf0[0] = *(const float4*)(&U[c * 132 + x0]);
      *(float4*)&uf1[0] = *(const float4*)(&U[(c + 1) * 132 + x0]);
#pragma unroll
      for (int jy = 0; jy < 8; ++jy)
#pragma unroll
        for (int jx = 0; jx < 4; ++jx) {
          Pa[jy][jx] += tf0[jy] * uf0[jx];
          Qa[jy][jx] += tf1[jy] * uf1[jx];
        }
    }
    {  // c = 60 (even -> P)
      float tf0[8], uf0[4];
      *(float4*)&tf0[0] = *(const float4*)(&T[60 * 64 + y0]);
      *(float4*)&tf0[4] = *(const float4*)(&T[60 * 64 + y0 + 4]);
      *(float4*)&uf0[0] = *(const float4*)(&U[60 * 132 + x0]);
#pragma unroll
      for (int jy = 0; jy < 8; ++jy)
#pragma unroll
        for (int jx = 0; jx < 4; ++jx) Pa[jy][jx] += tf0[jy] * uf0[jx];
    }
    const float bo_ = bias[o];
    float* op = out + (size_t)(b * 64 + o) * 16384;
#pragma unroll
    for (int jy = 0; jy < 8; ++jy) {
      float4 lo, hi;
      lo.x = Pa[jy][0] + Qa[jy][0] + bo_;
      lo.y = Pa[jy][1] + Qa[jy][1] + bo_;
      lo.z = Pa[jy][2] + Qa[jy][2] + bo_;
      lo.w = Pa[jy][3] + Qa[jy][3] + bo_;
      hi.x = Pa[jy][0] - Qa[jy][0] + bo_;
      hi.y = Pa[jy][1] - Qa[jy][1] + bo_;
      hi.z = Pa[jy][2] - Qa[jy][2] + bo_;
      hi.w = Pa[jy][3] - Qa[jy][3] + bo_;
      *(float4*)(op + (y0 + jy) * 128 + x0) = lo;
      *(float4*)(op + (y0 + jy + 64) * 128 + x0) = hi;
    }
  }
}

extern "C" void kernel_launch(void* const* d_in, const int* in_sizes, int n_in,
                              void* d_out, int out_size, void* d_ws, size_t ws_size,
                              hipStream_t stream) {
  (void)in_sizes; (void)n_in; (void)out_size; (void)ws_size;
  const float* x = (const float*)d_in[0];
  const float* w = (const float*)d_in[1];
  const float* bias = (const float*)d_in[2];
  float* out = (float*)d_out;

  unsigned* Wt = (unsigned*)d_ws;
  float* A = (float*)d_ws + 7745536;    // X2, later FT
  float* B = (float*)d_ws + 11618304;   // X2T, in-place F

  k0_what<<<976, 256, 0, stream>>>(w, Wt);
  k12_fwd<<<1024, 256, 0, stream>>>(x, A);
  ktx<<<480, 256, 0, stream>>>((const float2*)A, (float2*)B);
  k3_mfma<<<946, 256, 0, stream>>>(B, Wt, B);
  ktf<<<480, 256, 0, stream>>>((const float2*)B, (float2*)A);
  k45_out<<<1024, 256, 0, stream>>>(A, bias, out);
}